// Round 10
// baseline (3268.409 us; speedup 1.0000x reference)
//
#include <hip/hip_runtime.h>
#include <hip/hip_bf16.h>
#include <stdint.h>

// ---------------------------------------------------------------------------
// LinearFLHGS: per-group(64) symmetric int4 quant-dequant of x and w, then
// C = x_dq @ w_dq^T.  Round 10: round-9 structure with the scale-staging bug
// fixed.  global_load_lds has PER-LANE global source + linear LDS dest
// (base + lane*4): round 9 passed a wave-uniform scale pointer, broadcasting
// row-0's scale to all 64 rows of each half-band (absmax 3.23).  Fix: +lane.
// Exact int4 path: 128x128 tile, 4 waves, (256,3); per K-tile 16x
// mfma_i32_16x16x64_i8 + VALU fixup acc += cvt(iv)*sa*sb; scales staged via
// LDS 2 tiles ahead; frag+scale ds_reads hoisted to end of prev tile;
// vmcnt(5) steady state; both-sides XOR swizzle (0 conflicts, r7/r8).
// ---------------------------------------------------------------------------

typedef int   int32x4 __attribute__((ext_vector_type(4)));
typedef float f32x4   __attribute__((ext_vector_type(4)));

__global__ void quant_kernel(const float* __restrict__ in,
                             int8_t* __restrict__ qout,
                             float* __restrict__ sT,
                             int total4, int nrows) {
    int nth = gridDim.x * blockDim.x;
    int t0 = blockIdx.x * blockDim.x + threadIdx.x;
    for (int i = t0; i < total4; i += nth) {
        float4 v = ((const float4*)in)[i];
        float amax = fmaxf(fmaxf(fabsf(v.x), fabsf(v.y)),
                           fmaxf(fabsf(v.z), fabsf(v.w)));
        #pragma unroll
        for (int m = 1; m <= 8; m <<= 1)
            amax = fmaxf(amax, __shfl_xor(amax, m, 64));
        float s = fmaxf(amax / 7.0f, 1e-8f);
        int q0 = (int)fminf(fmaxf(rintf(v.x / s), -8.0f), 7.0f);
        int q1 = (int)fminf(fmaxf(rintf(v.y / s), -8.0f), 7.0f);
        int q2 = (int)fminf(fmaxf(rintf(v.z / s), -8.0f), 7.0f);
        int q3 = (int)fminf(fmaxf(rintf(v.w / s), -8.0f), 7.0f);
        uint32_t packed = (uint32_t)(q0 & 255) | ((uint32_t)(q1 & 255) << 8) |
                          ((uint32_t)(q2 & 255) << 16) | ((uint32_t)(q3 & 255) << 24);
        ((uint32_t*)qout)[i] = packed;
        if ((i & 15) == 0) {
            int row = i >> 10;          // K/4 = 1024 float4 per row (K=4096)
            int gir = (i & 1023) >> 4;
            sT[(size_t)gir * nrows + row] = s;
        }
    }
}

#define BM 128
#define BN 128

#define FENCE() asm volatile("" ::: "memory")

__global__ __launch_bounds__(256, 3) void gemm_kernel(
        const int8_t* __restrict__ A, const int8_t* __restrict__ B,
        const float* __restrict__ sAT, const float* __restrict__ sBT,
        float* __restrict__ C, int M, int N, int K) {
    __shared__ int8_t As[2][128 * 64];   // 8 KB each buf
    __shared__ int8_t Bs[2][128 * 64];
    __shared__ float  sAl[2][128];       // per-tile A scales
    __shared__ float  sBl[2][128];       // per-tile B scales

    const int NTt = K >> 6;   // 64 K-tiles == scale groups

    int nwg = gridDim.x;
    int bid = blockIdx.x;
    int swz = bid;
    if ((nwg & 7) == 0) {
        int cpx = nwg >> 3;
        swz = (bid & 7) * cpx + (bid >> 3);
    }
    int nbn = N / BN;
    int bm = swz / nbn, bn = swz % nbn;

    int tid = threadIdx.x;
    int lane = tid & 63;
    int wid = tid >> 6;       // 0..3
    int wr = wid >> 1;        // 0..1 : 64-row band of A
    int wc = wid & 1;         // 0..1 : 64-col band of B

    const int rowA0 = bm * BM;
    const int colB0 = bn * BN;

    // fragment reads: row rl=l&15, phys chunk = (l>>4) ^ ((rl>>1)&3)
    int rl = lane & 15;
    int cR = lane >> 4;
    int rsw = (cR ^ ((rl >> 1) & 3)) << 4;
    int rq = cR * 4;          // acc-reg row base (D map)

    // staging: lane -> row R0+(l>>2), phys chunk l&3; global logical chunk:
    int sgc = ((lane & 3) ^ ((lane >> 3) & 3)) << 4;

    f32x4 acc[4][4] = {};

    const int8_t* Ag = A + (size_t)rowA0 * K;
    const int8_t* Bg = B + (size_t)colB0 * K;

    // 5 global_load_lds per wave per tile: 2 A-frag, 2 B-frag, 1 scale
    auto stage = [&](int buf, int t) {
        #pragma unroll
        for (int j = 0; j < 2; ++j) {
            int R0 = wid * 32 + j * 16;
            const int8_t* g = Ag + (size_t)(R0 + (lane >> 2)) * K + t * 64 + sgc;
            __builtin_amdgcn_global_load_lds(
                (const __attribute__((address_space(1))) void*)g,
                (__attribute__((address_space(3))) void*)&As[buf][R0 * 64], 16, 0, 0);
        }
        #pragma unroll
        for (int j = 0; j < 2; ++j) {
            int R0 = wid * 32 + j * 16;
            const int8_t* g = Bg + (size_t)(R0 + (lane >> 2)) * K + t * 64 + sgc;
            __builtin_amdgcn_global_load_lds(
                (const __attribute__((address_space(1))) void*)g,
                (__attribute__((address_space(3))) void*)&Bs[buf][R0 * 64], 16, 0, 0);
        }
        // scales: wid0/1 -> A halves, wid2/3 -> B halves (64 floats each).
        // PER-LANE source (+lane): lane l fetches scale of row l of the band;
        // LDS dest scatter is base + lane*4.  (Round-9 bug: uniform source.)
        const float* gs;
        float* ls;
        if (wid < 2) { gs = sAT + (size_t)t * M + rowA0 + wid * 64;       ls = &sAl[buf][wid * 64]; }
        else         { gs = sBT + (size_t)t * N + colB0 + (wid - 2) * 64; ls = &sBl[buf][(wid - 2) * 64]; }
        __builtin_amdgcn_global_load_lds(
            (const __attribute__((address_space(1))) void*)(gs + lane),
            (__attribute__((address_space(3))) void*)ls, 4, 0, 0);
    };

    // loop-carried fragment + scale registers
    int32x4 av[4], bv[4];
    f32x4 sa[4];
    float sb_s[4];

    auto readFrags = [&](int cb) {
        #pragma unroll
        for (int ni = 0; ni < 4; ++ni)
            bv[ni] = *(const int32x4*)&Bs[cb][(wc * 64 + ni * 16 + rl) * 64 + rsw];
        #pragma unroll
        for (int mi = 0; mi < 4; ++mi)
            av[mi] = *(const int32x4*)&As[cb][(wr * 64 + mi * 16 + rl) * 64 + rsw];
        #pragma unroll
        for (int mi = 0; mi < 4; ++mi)
            sa[mi] = *(const f32x4*)&sAl[cb][wr * 64 + mi * 16 + rq];
        #pragma unroll
        for (int ni = 0; ni < 4; ++ni)
            sb_s[ni] = sBl[cb][wc * 64 + ni * 16 + rl];
    };

    const int32x4 zero = {0, 0, 0, 0};

    // ---- prologue ----
    stage(0, 0);
    stage(1, 1);
    asm volatile("s_waitcnt vmcnt(5)" ::: "memory");   // tile 0 landed
    FENCE(); __builtin_amdgcn_s_barrier(); FENCE();
    readFrags(0);

    for (int t = 0; t < NTt; ++t) {
        int cb = t & 1, nb = cb ^ 1;
        const bool more2 = (t + 2 < NTt);

        // ---- half A (mi 0,1): MFMA + fixup (operands already in regs) ----
        #pragma unroll
        for (int mi = 0; mi < 2; ++mi) {
            int32x4 iv[4];
            #pragma unroll
            for (int ni = 0; ni < 4; ++ni)
                iv[ni] = __builtin_amdgcn_mfma_i32_16x16x64_i8(av[mi], bv[ni], zero, 0, 0, 0);
            #pragma unroll
            for (int ni = 0; ni < 4; ++ni) {
                f32x4 sab = sa[mi] * sb_s[ni];
                #pragma unroll
                for (int r = 0; r < 4; ++r)
                    acc[mi][ni][r] += (float)iv[ni][r] * sab[r];
            }
        }

        // ---- seal ALL reads of buf[cb] (frag+scale, issued last tile) ----
        asm volatile("s_waitcnt lgkmcnt(0)" ::: "memory");
        FENCE(); __builtin_amdgcn_s_barrier(); FENCE();
        if (more2) stage(cb, t + 2);          // overwrite cb; hides under half B

        // ---- half B (mi 2,3) ----
        #pragma unroll
        for (int mi = 2; mi < 4; ++mi) {
            int32x4 iv[4];
            #pragma unroll
            for (int ni = 0; ni < 4; ++ni)
                iv[ni] = __builtin_amdgcn_mfma_i32_16x16x64_i8(av[mi], bv[ni], zero, 0, 0, 0);
            #pragma unroll
            for (int ni = 0; ni < 4; ++ni) {
                f32x4 sab = sa[mi] * sb_s[ni];
                #pragma unroll
                for (int r = 0; r < 4; ++r)
                    acc[mi][ni][r] += (float)iv[ni][r] * sab[r];
            }
        }

        // ---- t+1 landed (counted), cross-wave visible, then hoisted reads --
        if (more2) asm volatile("s_waitcnt vmcnt(5)" ::: "memory");
        else       asm volatile("s_waitcnt vmcnt(0)" ::: "memory");
        FENCE(); __builtin_amdgcn_s_barrier(); FENCE();
        if (t + 1 < NTt) readFrags(nb);       // drains under next half-A MFMAs
    }

    // ---- epilogue: D map col = lane&15, row = (lane>>4)*4 + reg ----
    int cl = lane & 15;
    #pragma unroll
    for (int mi = 0; mi < 4; ++mi) {
        #pragma unroll
        for (int ni = 0; ni < 4; ++ni) {
            int row = rowA0 + wr * 64 + mi * 16 + rq;
            int col = colB0 + wc * 64 + ni * 16 + cl;
            float* cp = C + (size_t)row * N + col;
            #pragma unroll
            for (int r = 0; r < 4; ++r)
                cp[(size_t)r * N] = acc[mi][ni][r];
        }
    }
}

extern "C" void kernel_launch(void* const* d_in, const int* in_sizes, int n_in,
                              void* d_out, int out_size, void* d_ws, size_t ws_size,
                              hipStream_t stream) {
    const float* x = (const float*)d_in[0];
    const float* w = (const float*)d_in[1];
    float* out = (float*)d_out;

    const int K = 4096;
    const int T = in_sizes[0] / K;   // 8192
    const int O = in_sizes[1] / K;   // 4096

    int8_t* qx  = (int8_t*)d_ws;                                  // T*K i8
    int8_t* qw  = qx + (size_t)T * K;                             // O*K i8
    float*  sxT = (float*)(qw + (size_t)O * K);                   // [K/64][T]
    float*  swT = sxT + (size_t)(K / 64) * T;                     // [K/64][O]

    quant_kernel<<<2048, 256, 0, stream>>>(x, qx, sxT, (T * K) >> 2, T);
    quant_kernel<<<2048, 256, 0, stream>>>(w, qw, swT, (O * K) >> 2, O);

    int nwg = (T / BM) * (O / BN);   // 64*32 = 2048
    gemm_kernel<<<nwg, 256, 0, stream>>>(qx, qw, sxT, swT, out, T, O, K);
}

// Round 11
// 320.254 us; speedup vs baseline: 10.2057x; 10.2057x over previous
//
#include <hip/hip_runtime.h>
#include <hip/hip_bf16.h>
#include <stdint.h>

// ---------------------------------------------------------------------------
// LinearFLHGS: per-group(64) symmetric int4 quant-dequant of x and w, then
// C = x_dq @ w_dq^T.  Round 11: bf16 8-phase 256x256 GEMM with the m201
// template's FULL prefetch depth.  2 K-tiles/iter (u->buf0, v->buf1, parity-
// fixed), 8 phases/iter; stages at ph{1,3,4,4,5,7,8,8}; vmcnt(6) ONLY at
// ph4/ph8 (drains loads >=3 phases old, > HBM latency -> no latency clamp);
// prologue = T0 full + T1{Bh0,Bh1,Ah0}, vmcnt(6).  Slot-liveness ledger:
// buf.B free after bHi-phase end-barrier, buf.A free after aHi-phase end-
// barrier; every stage lands 2+ phases after its slot's seal.  Tail: guards +
// vmcnt(0) on last iter.  Swizzle/setprio/epilogue/quant proven r1-r4.
// ---------------------------------------------------------------------------

typedef __bf16 bf16x8 __attribute__((ext_vector_type(8)));
typedef float f32x4 __attribute__((ext_vector_type(4)));

static __device__ __forceinline__ uint16_t f32_to_bf16_rne(float f) {
    uint32_t u = __float_as_uint(f);
    uint32_t r = (u + 0x7fffu + ((u >> 16) & 1u)) >> 16;
    return (uint16_t)r;
}

__global__ void quant_kernel(const float* __restrict__ in,
                             uint16_t* __restrict__ out, int total4) {
    int nthreads = gridDim.x * blockDim.x;
    int t = blockIdx.x * blockDim.x + threadIdx.x;
    for (int i = t; i < total4; i += nthreads) {
        float4 v = ((const float4*)in)[i];
        float amax = fmaxf(fmaxf(fabsf(v.x), fabsf(v.y)),
                           fmaxf(fabsf(v.z), fabsf(v.w)));
        #pragma unroll
        for (int m = 1; m <= 8; m <<= 1)
            amax = fmaxf(amax, __shfl_xor(amax, m, 64));
        float s = fmaxf(amax / 7.0f, 1e-8f);
        float q0 = fminf(fmaxf(rintf(v.x / s), -8.0f), 7.0f);
        float q1 = fminf(fmaxf(rintf(v.y / s), -8.0f), 7.0f);
        float q2 = fminf(fmaxf(rintf(v.z / s), -8.0f), 7.0f);
        float q3 = fminf(fmaxf(rintf(v.w / s), -8.0f), 7.0f);
        ushort4 o;
        o.x = f32_to_bf16_rne(q0 * s);
        o.y = f32_to_bf16_rne(q1 * s);
        o.z = f32_to_bf16_rne(q2 * s);
        o.w = f32_to_bf16_rne(q3 * s);
        ((ushort4*)out)[i] = o;
    }
}

#define BM 256
#define BN 256
#define BK 64

#define FENCE() asm volatile("" ::: "memory")
#define SB0()   __builtin_amdgcn_sched_barrier(0)

#define PH_MID() \
    FENCE(); __builtin_amdgcn_s_barrier(); \
    asm volatile("s_waitcnt lgkmcnt(0)" ::: "memory"); \
    SB0(); \
    __builtin_amdgcn_s_setprio(1);

#define PH_END() \
    __builtin_amdgcn_s_setprio(0); \
    FENCE(); __builtin_amdgcn_s_barrier(); FENCE();

__global__ __launch_bounds__(512, 2) void gemm_kernel(
        const uint16_t* __restrict__ A, const uint16_t* __restrict__ B,
        float* __restrict__ C, int M, int N, int K) {
    // [buf][half][128 rows][64 k] bf16 = 16 KB each; total 128 KB
    __shared__ uint16_t As[2][2][128 * 64];
    __shared__ uint16_t Bs[2][2][128 * 64];

    const int NTt = K >> 6;          // 64 K-tiles (even)
    const int NIter = NTt >> 1;      // 32 iterations of 2 tiles

    int nwg = gridDim.x;
    int bid = blockIdx.x;
    int swz = bid;
    if ((nwg & 7) == 0) {            // bijective XCD swizzle (nwg=512)
        int cpx = nwg >> 3;
        swz = (bid & 7) * cpx + (bid >> 3);
    }
    int nbn = N / BN;
    int bm = swz / nbn, bn = swz % nbn;

    int tid = threadIdx.x;
    int lane = tid & 63;
    int wid = tid >> 6;              // 0..7
    int wm = wid >> 2;               // 0..1 : 128-row band of A
    int wn = wid & 3;                // 0..3 : 64-col band of B

    const int rowA0 = bm * BM;
    const int colB0 = bn * BN;

    // staging: linear LDS dest, inverse-swizzled global src (rule #21)
    int srow = lane >> 3;
    int scol = ((lane & 7) ^ (lane >> 3)) << 3;

    // reads: swizzled ds_read addr (0 bank conflicts, measured r1-r4)
    int rl = lane & 15;
    int cg = lane >> 4;
    int coff[2];
    coff[0] = ((0 + cg) ^ (rl & 7)) << 3;
    coff[1] = ((4 + cg) ^ (rl & 7)) << 3;

    const int bhalf = wn >> 1;
    const int brow0 = (wn & 1) * 64;

    f32x4 acc[8][4] = {};
    bf16x8 aLo[4][2], aHi[4][2], bLo[2][2], bHi[2][2];

    auto stageA = [&](int buf, int half, int t) {
        #pragma unroll
        for (int j = 0; j < 2; ++j) {
            int rowin = wid * 16 + j * 8;
            const uint16_t* g = A + (size_t)(rowA0 + half * 128 + rowin + srow) * K
                                  + t * 64 + scol;
            uint16_t* l = &As[buf][half][rowin * 64];
            __builtin_amdgcn_global_load_lds(
                (const __attribute__((address_space(1))) void*)g,
                (__attribute__((address_space(3))) void*)l, 16, 0, 0);
        }
    };
    auto stageB = [&](int buf, int half, int t) {
        #pragma unroll
        for (int j = 0; j < 2; ++j) {
            int rowin = wid * 16 + j * 8;
            const uint16_t* g = B + (size_t)(colB0 + half * 128 + rowin + srow) * K
                                  + t * 64 + scol;
            uint16_t* l = &Bs[buf][half][rowin * 64];
            __builtin_amdgcn_global_load_lds(
                (const __attribute__((address_space(1))) void*)g,
                (__attribute__((address_space(3))) void*)l, 16, 0, 0);
        }
    };

    auto readA = [&](bf16x8 (&dst)[4][2], int lo, int buf) {
        #pragma unroll
        for (int mi = 0; mi < 4; ++mi)
            #pragma unroll
            for (int ks = 0; ks < 2; ++ks)
                dst[mi][ks] = *(const bf16x8*)&As[buf][wm][((lo + mi) * 16 + rl) * 64 + coff[ks]];
    };
    auto readB = [&](bf16x8 (&dst)[2][2], int lo, int buf) {
        #pragma unroll
        for (int ni = 0; ni < 2; ++ni)
            #pragma unroll
            for (int ks = 0; ks < 2; ++ks)
                dst[ni][ks] = *(const bf16x8*)&Bs[buf][bhalf][(brow0 + (lo + ni) * 16 + rl) * 64 + coff[ks]];
    };

    auto quadQ = [&](const bf16x8 (&af)[4][2], const bf16x8 (&bf)[2][2],
                     int mo, int no) {
        #pragma unroll
        for (int mi = 0; mi < 4; ++mi)
            #pragma unroll
            for (int ni = 0; ni < 2; ++ni)
                #pragma unroll
                for (int ks = 0; ks < 2; ++ks)
                    acc[mo + mi][no + ni] = __builtin_amdgcn_mfma_f32_16x16x32_bf16(
                        af[mi][ks], bf[ni][ks], acc[mo + mi][no + ni], 0, 0, 0);
    };

    // ---- prologue: T0 full + T1{Bh0,Bh1,Ah0}; vmcnt(6) drains T0 ----
    stageA(0, 0, 0); stageA(0, 1, 0); stageB(0, 0, 0); stageB(0, 1, 0);
    stageB(1, 0, 1); stageB(1, 1, 1); stageA(1, 0, 1);
    asm volatile("s_waitcnt vmcnt(6)" ::: "memory");
    FENCE(); __builtin_amdgcn_s_barrier(); FENCE();

    for (int i = 0; i < NIter; ++i) {
        int u = 2 * i, v = u + 1;
        const bool g2 = (u + 2 < NTt), g3 = (u + 3 < NTt);
        const bool last = (i == NIter - 1);

        // ph1: reads aLo(u)+bLo(u) @buf0 (12); stage A(v)h1 -> buf1
        readA(aLo, 0, 0); readB(bLo, 0, 0);
        stageA(1, 1, v);
        asm volatile("s_waitcnt lgkmcnt(8)" ::: "memory");
        PH_MID(); quadQ(aLo, bLo, 0, 0); PH_END();

        // ph2: reads bHi(u) (4)
        readB(bHi, 2, 0);
        PH_MID(); quadQ(aLo, bHi, 0, 2); PH_END();

        // ph3: reads aHi(u) (8); stage B(u+2)h0 -> buf0 (B slot sealed ph2)
        readA(aHi, 4, 0);
        if (g2) stageB(0, 0, u + 2);
        PH_MID(); quadQ(aHi, bLo, 4, 0); PH_END();

        // ph4: stage B(u+2)h1 + A(u+2)h0 (A slot sealed ph3); vmcnt(6)
        if (g2) { stageB(0, 1, u + 2); stageA(0, 0, u + 2); }
        if (last) asm volatile("s_waitcnt vmcnt(0)" ::: "memory");
        else      asm volatile("s_waitcnt vmcnt(6)" ::: "memory");
        PH_MID(); quadQ(aHi, bHi, 4, 2); PH_END();

        // ph5: reads aLo(v)+bLo(v) @buf1 (12); stage A(u+2)h1
        readA(aLo, 0, 1); readB(bLo, 0, 1);
        if (g2) stageA(0, 1, u + 2);
        asm volatile("s_waitcnt lgkmcnt(8)" ::: "memory");
        PH_MID(); quadQ(aLo, bLo, 0, 0); PH_END();

        // ph6: reads bHi(v) (4)
        readB(bHi, 2, 1);
        PH_MID(); quadQ(aLo, bHi, 0, 2); PH_END();

        // ph7: reads aHi(v) (8); stage B(u+3)h0 -> buf1 (sealed ph6)
        readA(aHi, 4, 1);
        if (g3) stageB(1, 0, u + 3);
        PH_MID(); quadQ(aHi, bLo, 4, 0); PH_END();

        // ph8: stage B(u+3)h1 + A(u+3)h0 (sealed ph7); vmcnt(6)
        if (g3) { stageB(1, 1, u + 3); stageA(1, 0, u + 3); }
        if (last) asm volatile("s_waitcnt vmcnt(0)" ::: "memory");
        else      asm volatile("s_waitcnt vmcnt(6)" ::: "memory");
        PH_MID(); quadQ(aHi, bHi, 4, 2); PH_END();
    }

    // ---- epilogue: D map col = lane&15, row = (lane>>4)*4 + reg ----
    int cl = lane & 15;
    int rq = (lane >> 4) * 4;
    #pragma unroll
    for (int mi = 0; mi < 8; ++mi) {
        #pragma unroll
        for (int ni = 0; ni < 4; ++ni) {
            int row = rowA0 + wm * 128 + mi * 16 + rq;
            int col = colB0 + wn * 64 + ni * 16 + cl;
            float* cp = C + (size_t)row * N + col;
            #pragma unroll
            for (int r = 0; r < 4; ++r)
                cp[(size_t)r * N] = acc[mi][ni][r];
        }
    }
}

extern "C" void kernel_launch(void* const* d_in, const int* in_sizes, int n_in,
                              void* d_out, int out_size, void* d_ws, size_t ws_size,
                              hipStream_t stream) {
    const float* x = (const float*)d_in[0];
    const float* w = (const float*)d_in[1];
    float* out = (float*)d_out;

    const int K = 4096;
    const int T = in_sizes[0] / K;   // 8192
    const int O = in_sizes[1] / K;   // 4096

    uint16_t* xq = (uint16_t*)d_ws;                                  // T*K bf16
    uint16_t* wq = (uint16_t*)((char*)d_ws + (size_t)T * K * 2);     // O*K bf16

    quant_kernel<<<2048, 256, 0, stream>>>(x, xq, (T * K) >> 2);
    quant_kernel<<<2048, 256, 0, stream>>>(w, wq, (O * K) >> 2);

    int nwg = (T / BM) * (O / BN);   // 32*16 = 512
    gemm_kernel<<<nwg, 512, 0, stream>>>(xq, wq, out, T, O, K);
}